// Round 2
// baseline (223.981 us; speedup 1.0000x reference)
//
#include <hip/hip_runtime.h>

typedef unsigned short u16;
typedef unsigned int   u32;

#define NN     65536      // nodes = B*L = 8*8192
#define DDIM   128        // feature dim = H*C
#define EE     1048576    // edges (self loop handled inline, not in CSR)
#define NEG_SLOPE 0.2f
#define SUBCAP 768        // per (bucket, xcd-slot) capacity; mean 512

typedef __attribute__((ext_vector_type(8))) short          short8;
typedef __attribute__((ext_vector_type(2))) float          f32x2;
typedef __attribute__((ext_vector_type(4))) float          f32x4;
typedef __attribute__((ext_vector_type(4))) u32            u32x4;

__device__ __forceinline__ float bf2f(u16 b) { return __uint_as_float(((u32)b) << 16); }
__device__ __forceinline__ u16 f2bf(float f) {
  u32 u = __float_as_uint(f);
  u += 0x7FFFu + ((u >> 16) & 1u);   // round-to-nearest-even
  return (u16)(u >> 16);
}
__device__ __forceinline__ f32x2 bfp2f(u32 w) {
  f32x2 r;
  r.x = __uint_as_float(w << 16);
  r.y = __uint_as_float(w & 0xFFFF0000u);
  return r;
}
__device__ __forceinline__ f32x2 pk_max(f32x2 a, f32x2 b) {
  f32x2 r; r.x = fmaxf(a.x, b.x); r.y = fmaxf(a.y, b.y); return r;
}

// ---- init: b0 = dtype detect; b1..b8 = W pack (parallel); b9..b16 = cursors -
__global__ void init_misc(const int* __restrict__ ei, u32* __restrict__ mode,
                          const float* __restrict__ Wl, const float* __restrict__ Wr,
                          u16* __restrict__ wpack, u32* __restrict__ cursor) {
  int t = threadIdx.x, b = blockIdx.x;
  if (b == 0) {
    if (t < 64) {
      int nz = (ei[2 * t + 1] != 0) ? 1 : 0;   // int64 storage => high words zero
      unsigned long long bal = __ballot(nz);
      if (t == 0) mode[0] = (bal == 0ull) ? 1u : 0u;   // 1 = int64
    }
    return;
  }
  if (b <= 8) {
    // one block per (colhalf, ks); 256 threads = 4 p-groups x 64 lanes; 2 p iters
    int pb = b - 1;
    int colhalf = pb >> 2, ks = pb & 3;
    int lane = t & 63, pp = t >> 6;
    int m16 = lane & 15, quad = lane >> 4;
#pragma unroll
    for (int pq = 0; pq < 2; ++pq) {
      int p = pq * 4 + pp;                     // 0..3 = Wl ct, 4..7 = Wr ct
      const float* W = (p < 4) ? Wl : Wr;
      int n = colhalf * 64 + (p & 3) * 16 + m16;
#pragma unroll
      for (int j = 0; j < 8; ++j) {
        int k = ks * 32 + quad * 8 + j;
        wpack[(((((colhalf * 4 + ks) * 8) + p) * 64 + lane) * 8) + j] = f2bf(W[k * DDIM + n]);
      }
    }
    return;
  }
  // b = 9..16: zero cursor lines (2048 sub-buckets x 16 u32)
  int i = (b - 9) * 256 + t;
#pragma unroll
  for (int k = 0; k < 16; ++k) cursor[i * 16 + k] = 0;
}

// ---------------- GEMM body: xl = x@Wl, xr = x@Wr (bf16 MFMA) ---------------
__device__ __forceinline__ void gemm_body(
    int pb, int tid,
    const float* __restrict__ x, const u16* __restrict__ wpack,
    u16* __restrict__ xl, u16* __restrict__ xr)
{
  int wave = tid >> 6;
  int lane = tid & 63;
  int m16  = lane & 15;
  int quad = lane >> 4;
  int mat     = wave >> 1;     // 0 = Wl -> xl, 1 = Wr -> xr
  int colhalf = wave & 1;
  int rowbase = pb * 64;

  const u16* wp = wpack + (size_t)colhalf * (4 * 8 * 64 * 8);
  short8 bfr[4][4];
#pragma unroll
  for (int ks = 0; ks < 4; ++ks)
#pragma unroll
    for (int ct = 0; ct < 4; ++ct)
      bfr[ks][ct] = *(const short8*)(wp + ((size_t)(ks * 8 + mat * 4 + ct) * 64 + lane) * 8);

  u16* outp = mat ? xr : xl;
#pragma unroll
  for (int rt = 0; rt < 4; ++rt) {
    int r0 = rowbase + rt * 16;
    f32x4 acc[4] = { {0,0,0,0},{0,0,0,0},{0,0,0,0},{0,0,0,0} };
#pragma unroll
    for (int ks = 0; ks < 4; ++ks) {
      const float* ap = x + (size_t)(r0 + m16) * DDIM + ks * 32 + quad * 8;
      f32x4 a0 = *(const f32x4*)ap;
      f32x4 a1 = *(const f32x4*)(ap + 4);
      short8 a;
#pragma unroll
      for (int c = 0; c < 4; ++c) { a[c] = (short)f2bf(a0[c]); a[4 + c] = (short)f2bf(a1[c]); }
#pragma unroll
      for (int ct = 0; ct < 4; ++ct)
        acc[ct] = __builtin_amdgcn_mfma_f32_16x16x32_bf16(a, bfr[ks][ct], acc[ct], 0, 0, 0);
    }
#pragma unroll
    for (int ct = 0; ct < 4; ++ct) {
      int c = colhalf * 64 + ct * 16 + m16;
#pragma unroll
      for (int rg = 0; rg < 4; ++rg) {
        int r = r0 + quad * 4 + rg;
        outp[(size_t)r * DDIM + c] = f2bf(acc[ct][rg]);
      }
    }
  }
}

// ---------------- pass1 body: bin edges by dst>>8 into 256 x 8 slots --------
// Launched as blocks [1024,2048): XCD(1024+pb) = pb&7 (1024%8==0), so slot
// xs = pb&7 keeps every cursor slot written from exactly one XCD (L2-local
// atomics) while pass1 work spreads over ALL 8 XCDs.
__device__ __forceinline__ void pass1_body(
    int pb, int tid,
    const int* __restrict__ ei, u32* __restrict__ cursor,
    u32* __restrict__ subb, const u32* __restrict__ mode)
{
  int base = (pb * 256 + tid) * 4;   // covers EE/4 exactly over 1024 sub-blocks
  int s[4], d[4];
  if (mode[0]) {
    const long long* ei64 = (const long long*)ei;
    longlong2 sa = *(const longlong2*)(ei64 + base);
    longlong2 sb = *(const longlong2*)(ei64 + base + 2);
    longlong2 da = *(const longlong2*)(ei64 + EE + base);
    longlong2 db = *(const longlong2*)(ei64 + EE + base + 2);
    s[0] = (int)sa.x; s[1] = (int)sa.y; s[2] = (int)sb.x; s[3] = (int)sb.y;
    d[0] = (int)da.x; d[1] = (int)da.y; d[2] = (int)db.x; d[3] = (int)db.y;
  } else {
    int4 sv = *(const int4*)(ei + base);
    int4 dv = *(const int4*)(ei + EE + base);
    s[0] = sv.x; s[1] = sv.y; s[2] = sv.z; s[3] = sv.w;
    d[0] = dv.x; d[1] = dv.y; d[2] = dv.z; d[3] = dv.w;
  }
  int xs = pb & 7;
#pragma unroll
  for (int i = 0; i < 4; ++i) {
    int sb_ = (d[i] >> 8) * 8 + xs;
    u32 p = atomicAdd(&cursor[sb_ * 16], 1u);
    if (p < SUBCAP) subb[(size_t)sb_ * SUBCAP + p] = ((u32)(d[i] & 255) << 16) | (u32)s[i];
  }
}

// ---------------- fused GEMM || pass1 (contiguous halves) -------------------
__global__ __launch_bounds__(256) void gemm_pass1(
    const float* __restrict__ x, const u16* __restrict__ wpack,
    u16* __restrict__ xl, u16* __restrict__ xr,
    const int* __restrict__ ei, u32* __restrict__ cursor,
    u32* __restrict__ subb, const u32* __restrict__ mode)
{
  int b = blockIdx.x;
  if (b < 1024) gemm_body(b, threadIdx.x, x, wpack, xl, xr);
  else          pass1_body(b - 1024, threadIdx.x, ei, cursor, subb, mode);
}

// ---------------- CSR build: per-bucket count + scan + place ----------------
// 1024 threads/block: count + place phases get 16 waves/CU of latency hiding;
// the 256-wide scan/meta phases are guarded by t<256.
__global__ __launch_bounds__(1024) void pass2_build(const u32* __restrict__ cursor,
                                                    const u32* __restrict__ subb,
                                                    u32* __restrict__ rowptr,
                                                    u16* __restrict__ csr,
                                                    u32* __restrict__ perm)
{
  __shared__ u32 sh[256];
  __shared__ u32 cnt[256];
  __shared__ u32 cur[256];
  __shared__ u32 hist[64];
  int b = blockIdx.x, t = threadIdx.x;

  if (t < 256) {
    u32 tot = 0;
#pragma unroll
    for (int x = 0; x < 8; ++x) tot += min(cursor[(t * 8 + x) * 16], (u32)SUBCAP);
    sh[t] = tot; cnt[t] = 0;
    if (t < 64) hist[t] = 0;
  }
  __syncthreads();
  for (int off = 1; off < 256; off <<= 1) {
    u32 v = 0, a = 0;
    if (t < 256) { v = sh[t]; a = (t >= off) ? sh[t - off] : 0u; }
    __syncthreads();
    if (t < 256) sh[t] = v + a;
    __syncthreads();
  }
  u32 base      = (b == 0) ? 0u : sh[b - 1];
  u32 total_all = sh[255];

  u32 sizes[8];
#pragma unroll
  for (int x = 0; x < 8; ++x) sizes[x] = min(cursor[(b * 8 + x) * 16], (u32)SUBCAP);

#pragma unroll
  for (int x = 0; x < 8; ++x) {
    const u32* sp = subb + (size_t)(b * 8 + x) * SUBCAP;
    u32 s = sizes[x];
    for (u32 i = t; i < s; i += 1024)
      atomicAdd(&cnt[sp[i] >> 16], 1u);
  }
  __syncthreads();

  u32 c = 0, dc = 0;
  if (t < 256) {
    c  = cnt[t];
    dc = min(c, 63u);
    atomicAdd(&hist[dc], 1u);                  // degree histogram
    sh[t] = c;
  }
  __syncthreads();
  for (int off = 1; off < 256; off <<= 1) {
    u32 v = 0, a = 0;
    if (t < 256) { v = sh[t]; a = (t >= off) ? sh[t - off] : 0u; }
    __syncthreads();
    if (t < 256) sh[t] = v + a;
    __syncthreads();
  }
  if (t < 256) {
    u32 loc = sh[t] - c;
    rowptr[b * 256 + t] = base + loc;
    cur[t] = loc;
  }
  if (b == 255 && t == 255) rowptr[NN] = total_all;
  __syncthreads();
  if (t == 0) {
    u32 run = 0;
    for (int i = 0; i < 64; ++i) { u32 h = hist[i]; hist[i] = run; run += h; }
  }
  __syncthreads();
  if (t < 256) {
    u32 r = atomicAdd(&hist[dc], 1u);          // rank within bucket by degree
    perm[b * 256 + r] = b * 256 + t;
  }
  __syncthreads();

#pragma unroll
  for (int x = 0; x < 8; ++x) {
    const u32* sp = subb + (size_t)(b * 8 + x) * SUBCAP;
    u32 s = sizes[x];
    for (u32 i = t; i < s; i += 1024) {
      u32 en = sp[i];
      u32 pos = atomicAdd(&cur[en >> 16], 1u);
      csr[base + pos] = (u16)(en & 0xFFFFu);
    }
  }
}

// ---------------- Fused attention + aggregation (no-max softmax) ------------
// Quarter-wave (16 lanes) per dst node, degree-sorted via perm (waves are
// degree-homogeneous). Ladder prefetch: issue ALL row-gathers of a 16/8/4
// chunk at once (named regs), sched_barrier(0) pins issue-before-consume,
// then consume in issue order -> counted vmcnt waits, up to 16 gathers in
// flight per 16-lane stream.
__device__ __forceinline__ void gat_item(u32x4 xw, const f32x2* av, const f32x2* rv,
                                         float& l, f32x2* acc)
{
  f32x2 xv[4];
  f32x2 sc2 = {0.f, 0.f};
#pragma unroll
  for (int i = 0; i < 4; ++i) {
    xv[i] = bfp2f(xw[i]);
    f32x2 t = xv[i] + rv[i];
    f32x2 lr = pk_max(t, t * NEG_SLOPE);        // leaky_relu
    sc2 += av[i] * lr;
  }
  float partial = sc2.x + sc2.y;
  partial += __shfl_xor(partial, 1);
  partial += __shfl_xor(partial, 2);
  partial += __shfl_xor(partial, 4);            // per-head score (8-lane group)
  float p = __expf(partial);
  l += p;
#pragma unroll
  for (int i = 0; i < 4; ++i) acc[i] += p * xv[i];
}

__global__ __launch_bounds__(256) void gat_fused(
    const u16* __restrict__ xl, const u16* __restrict__ xr,
    const u32* __restrict__ rowptr, const u16* __restrict__ csr,
    const u32* __restrict__ perm,
    const float* __restrict__ att, const float* __restrict__ bias,
    float* __restrict__ out)
{
  int tid  = threadIdx.x;
  int node = (int)perm[blockIdx.x * 16 + (tid >> 4)];
  int q    = tid & 15;
  int c0   = q * 8;
  const u16* __restrict__ xlc = xl + c0;

  // issue self-row gather early
  u32x4 SW = *(const u32x4*)(xlc + (size_t)node * DDIM);

  f32x2 av[4], rv[4];
  {
    f32x4 a0 = *(const f32x4*)(att + c0);
    f32x4 a1 = *(const f32x4*)(att + c0 + 4);
    av[0].x = a0[0]; av[0].y = a0[1]; av[1].x = a0[2]; av[1].y = a0[3];
    av[2].x = a1[0]; av[2].y = a1[1]; av[3].x = a1[2]; av[3].y = a1[3];
    u32x4 rw = *(const u32x4*)(xr + (size_t)node * DDIM + c0);
#pragma unroll
    for (int i = 0; i < 4; ++i) rv[i] = bfp2f(rw[i]);
  }

  float l = 0.f;
  f32x2 acc[4] = { {0,0},{0,0},{0,0},{0,0} };

  u32 rs  = rowptr[node];
  int deg = (int)(rowptr[node + 1] - rs);
  const u16* __restrict__ cp = csr + rs;

  gat_item(SW, av, rv, l, acc);                 // item 0 = self loop

  int j = 0;
  while (deg - j >= 16) {
    u32 i0  = cp[j+0],  i1  = cp[j+1],  i2  = cp[j+2],  i3  = cp[j+3];
    u32 i4  = cp[j+4],  i5  = cp[j+5],  i6  = cp[j+6],  i7  = cp[j+7];
    u32 i8  = cp[j+8],  i9  = cp[j+9],  i10 = cp[j+10], i11 = cp[j+11];
    u32 i12 = cp[j+12], i13 = cp[j+13], i14 = cp[j+14], i15 = cp[j+15];
    u32x4 L0  = *(const u32x4*)(xlc + (size_t)i0  * DDIM);
    u32x4 L1  = *(const u32x4*)(xlc + (size_t)i1  * DDIM);
    u32x4 L2  = *(const u32x4*)(xlc + (size_t)i2  * DDIM);
    u32x4 L3  = *(const u32x4*)(xlc + (size_t)i3  * DDIM);
    u32x4 L4  = *(const u32x4*)(xlc + (size_t)i4  * DDIM);
    u32x4 L5  = *(const u32x4*)(xlc + (size_t)i5  * DDIM);
    u32x4 L6  = *(const u32x4*)(xlc + (size_t)i6  * DDIM);
    u32x4 L7  = *(const u32x4*)(xlc + (size_t)i7  * DDIM);
    u32x4 L8  = *(const u32x4*)(xlc + (size_t)i8  * DDIM);
    u32x4 L9  = *(const u32x4*)(xlc + (size_t)i9  * DDIM);
    u32x4 L10 = *(const u32x4*)(xlc + (size_t)i10 * DDIM);
    u32x4 L11 = *(const u32x4*)(xlc + (size_t)i11 * DDIM);
    u32x4 L12 = *(const u32x4*)(xlc + (size_t)i12 * DDIM);
    u32x4 L13 = *(const u32x4*)(xlc + (size_t)i13 * DDIM);
    u32x4 L14 = *(const u32x4*)(xlc + (size_t)i14 * DDIM);
    u32x4 L15 = *(const u32x4*)(xlc + (size_t)i15 * DDIM);
    __builtin_amdgcn_sched_barrier(0);          // pin: all 16 issued before use
    gat_item(L0,  av, rv, l, acc);
    gat_item(L1,  av, rv, l, acc);
    gat_item(L2,  av, rv, l, acc);
    gat_item(L3,  av, rv, l, acc);
    gat_item(L4,  av, rv, l, acc);
    gat_item(L5,  av, rv, l, acc);
    gat_item(L6,  av, rv, l, acc);
    gat_item(L7,  av, rv, l, acc);
    gat_item(L8,  av, rv, l, acc);
    gat_item(L9,  av, rv, l, acc);
    gat_item(L10, av, rv, l, acc);
    gat_item(L11, av, rv, l, acc);
    gat_item(L12, av, rv, l, acc);
    gat_item(L13, av, rv, l, acc);
    gat_item(L14, av, rv, l, acc);
    gat_item(L15, av, rv, l, acc);
    j += 16;
  }
  if (deg - j >= 8) {
    u32 i0 = cp[j+0], i1 = cp[j+1], i2 = cp[j+2], i3 = cp[j+3];
    u32 i4 = cp[j+4], i5 = cp[j+5], i6 = cp[j+6], i7 = cp[j+7];
    u32x4 L0 = *(const u32x4*)(xlc + (size_t)i0 * DDIM);
    u32x4 L1 = *(const u32x4*)(xlc + (size_t)i1 * DDIM);
    u32x4 L2 = *(const u32x4*)(xlc + (size_t)i2 * DDIM);
    u32x4 L3 = *(const u32x4*)(xlc + (size_t)i3 * DDIM);
    u32x4 L4 = *(const u32x4*)(xlc + (size_t)i4 * DDIM);
    u32x4 L5 = *(const u32x4*)(xlc + (size_t)i5 * DDIM);
    u32x4 L6 = *(const u32x4*)(xlc + (size_t)i6 * DDIM);
    u32x4 L7 = *(const u32x4*)(xlc + (size_t)i7 * DDIM);
    __builtin_amdgcn_sched_barrier(0);
    gat_item(L0, av, rv, l, acc);
    gat_item(L1, av, rv, l, acc);
    gat_item(L2, av, rv, l, acc);
    gat_item(L3, av, rv, l, acc);
    gat_item(L4, av, rv, l, acc);
    gat_item(L5, av, rv, l, acc);
    gat_item(L6, av, rv, l, acc);
    gat_item(L7, av, rv, l, acc);
    j += 8;
  }
  if (deg - j >= 4) {
    u32 i0 = cp[j+0], i1 = cp[j+1], i2 = cp[j+2], i3 = cp[j+3];
    u32x4 L0 = *(const u32x4*)(xlc + (size_t)i0 * DDIM);
    u32x4 L1 = *(const u32x4*)(xlc + (size_t)i1 * DDIM);
    u32x4 L2 = *(const u32x4*)(xlc + (size_t)i2 * DDIM);
    u32x4 L3 = *(const u32x4*)(xlc + (size_t)i3 * DDIM);
    __builtin_amdgcn_sched_barrier(0);
    gat_item(L0, av, rv, l, acc);
    gat_item(L1, av, rv, l, acc);
    gat_item(L2, av, rv, l, acc);
    gat_item(L3, av, rv, l, acc);
    j += 4;
  }
  for (; j < deg; ++j) {
    u32 s = cp[j];
    u32x4 xw = *(const u32x4*)(xlc + (size_t)s * DDIM);
    gat_item(xw, av, rv, l, acc);
  }

  float inv = 1.f / l;
  f32x4 o0, o1;
  o0[0] = fmaf(acc[0].x, inv, bias[c0 + 0]);
  o0[1] = fmaf(acc[0].y, inv, bias[c0 + 1]);
  o0[2] = fmaf(acc[1].x, inv, bias[c0 + 2]);
  o0[3] = fmaf(acc[1].y, inv, bias[c0 + 3]);
  o1[0] = fmaf(acc[2].x, inv, bias[c0 + 4]);
  o1[1] = fmaf(acc[2].y, inv, bias[c0 + 5]);
  o1[2] = fmaf(acc[3].x, inv, bias[c0 + 6]);
  o1[3] = fmaf(acc[3].y, inv, bias[c0 + 7]);
  float* op = out + (size_t)node * DDIM + c0;
  *(f32x4*)op       = o0;
  *(f32x4*)(op + 4) = o1;
}

// ---------------- launch ----------------
extern "C" void kernel_launch(void* const* d_in, const int* in_sizes, int n_in,
                              void* d_out, int out_size, void* d_ws, size_t ws_size,
                              hipStream_t stream) {
  (void)in_sizes; (void)n_in; (void)out_size; (void)ws_size;
  const float* x    = (const float*)d_in[0];  // [N,128] fp32
  const int*   ei   = (const int*)d_in[1];    // [2,E] int64/int32 (detected)
  const float* Wl   = (const float*)d_in[2];  // [128,128] fp32
  const float* Wr   = (const float*)d_in[3];
  const float* attw = (const float*)d_in[4];  // [2,64] fp32
  const float* bias = (const float*)d_in[5];  // [128] fp32
  float* out = (float*)d_out;                 // [N,128] fp32

  char* w = (char*)d_ws;
  u16* xl     = (u16*)(w);                              // 16 MB
  u16* xr     = (u16*)(w + (16u << 20));                // 16 MB
  u32* subb   = (u32*)(w + (32u << 20));                // 6 MB
  u32* cursor = (u32*)(w + (38u << 20));                // 128 KB
  u32* mode   = (u32*)(w + (38u << 20) + (192u << 10)); // 8 B
  u32* rowptr = (u32*)(w + (38u << 20) + (256u << 10)); // 256 KB + 4
  u16* csr    = (u16*)(w + (39u << 20));                // 2 MB
  u16* wpack  = (u16*)(w + (41u << 20));                // 64 KB
  u32* perm   = (u32*)(w + (41u << 20) + (128u << 10)); // 256 KB

  init_misc<<<17, 256, 0, stream>>>(ei, mode, Wl, Wr, wpack, cursor);
  gemm_pass1<<<2048, 256, 0, stream>>>(x, wpack, xl, xr, ei, cursor, subb, mode);
  pass2_build<<<256, 1024, 0, stream>>>(cursor, subb, rowptr, csr, perm);
  gat_fused<<<NN / 16, 256, 0, stream>>>(xl, xr, rowptr, csr, perm, attw, bias, out);
}

// Round 3
// 195.964 us; speedup vs baseline: 1.1430x; 1.1430x over previous
//
#include <hip/hip_runtime.h>

typedef unsigned short u16;
typedef unsigned int   u32;

#define NN     65536      // nodes = B*L = 8*8192
#define DDIM   128        // feature dim = H*C
#define EE     1048576    // edges (self loop handled inline, not in CSR)
#define NEG_SLOPE 0.2f
#define SUBCAP 768        // per (bucket, xcd-slot) capacity; mean 512

typedef __attribute__((ext_vector_type(8))) short          short8;
typedef __attribute__((ext_vector_type(2))) float          f32x2;
typedef __attribute__((ext_vector_type(4))) float          f32x4;
typedef __attribute__((ext_vector_type(4))) u32            u32x4;

__device__ __forceinline__ float bf2f(u16 b) { return __uint_as_float(((u32)b) << 16); }
__device__ __forceinline__ u16 f2bf(float f) {
  u32 u = __float_as_uint(f);
  u += 0x7FFFu + ((u >> 16) & 1u);   // round-to-nearest-even
  return (u16)(u >> 16);
}
__device__ __forceinline__ f32x2 bfp2f(u32 w) {
  f32x2 r;
  r.x = __uint_as_float(w << 16);
  r.y = __uint_as_float(w & 0xFFFF0000u);
  return r;
}
__device__ __forceinline__ f32x2 pk_max(f32x2 a, f32x2 b) {
  f32x2 r; r.x = fmaxf(a.x, b.x); r.y = fmaxf(a.y, b.y); return r;
}

// ---- init: b0 = dtype detect; b1..b8 = W pack (parallel); b9..b16 = cursors -
__global__ void init_misc(const int* __restrict__ ei, u32* __restrict__ mode,
                          const float* __restrict__ Wl, const float* __restrict__ Wr,
                          u16* __restrict__ wpack, u32* __restrict__ cursor) {
  int t = threadIdx.x, b = blockIdx.x;
  if (b == 0) {
    if (t < 64) {
      int nz = (ei[2 * t + 1] != 0) ? 1 : 0;   // int64 storage => high words zero
      unsigned long long bal = __ballot(nz);
      if (t == 0) mode[0] = (bal == 0ull) ? 1u : 0u;   // 1 = int64
    }
    return;
  }
  if (b <= 8) {
    // one block per (colhalf, ks); 256 threads = 4 p-groups x 64 lanes; 2 p iters
    int pb = b - 1;
    int colhalf = pb >> 2, ks = pb & 3;
    int lane = t & 63, pp = t >> 6;
    int m16 = lane & 15, quad = lane >> 4;
#pragma unroll
    for (int pq = 0; pq < 2; ++pq) {
      int p = pq * 4 + pp;                     // 0..3 = Wl ct, 4..7 = Wr ct
      const float* W = (p < 4) ? Wl : Wr;
      int n = colhalf * 64 + (p & 3) * 16 + m16;
#pragma unroll
      for (int j = 0; j < 8; ++j) {
        int k = ks * 32 + quad * 8 + j;
        wpack[(((((colhalf * 4 + ks) * 8) + p) * 64 + lane) * 8) + j] = f2bf(W[k * DDIM + n]);
      }
    }
    return;
  }
  // b = 9..16: zero cursor lines (2048 sub-buckets x 16 u32)
  int i = (b - 9) * 256 + t;
#pragma unroll
  for (int k = 0; k < 16; ++k) cursor[i * 16 + k] = 0;
}

// ---------------- GEMM: xl = x@Wl, xr = x@Wr (bf16 MFMA, fp32 in, bf16 out) -
__global__ __launch_bounds__(256) void gemm_xlxr(
    const float* __restrict__ x, const u16* __restrict__ wpack,
    u16* __restrict__ xl, u16* __restrict__ xr)
{
  int tid  = threadIdx.x;
  int wave = tid >> 6;
  int lane = tid & 63;
  int m16  = lane & 15;
  int quad = lane >> 4;
  int mat     = wave >> 1;     // 0 = Wl -> xl, 1 = Wr -> xr
  int colhalf = wave & 1;
  int rowbase = blockIdx.x * 64;

  const u16* wp = wpack + (size_t)colhalf * (4 * 8 * 64 * 8);
  short8 bfr[4][4];
#pragma unroll
  for (int ks = 0; ks < 4; ++ks)
#pragma unroll
    for (int ct = 0; ct < 4; ++ct)
      bfr[ks][ct] = *(const short8*)(wp + ((size_t)(ks * 8 + mat * 4 + ct) * 64 + lane) * 8);

  u16* outp = mat ? xr : xl;
#pragma unroll
  for (int rt = 0; rt < 4; ++rt) {
    int r0 = rowbase + rt * 16;
    f32x4 acc[4] = { {0,0,0,0},{0,0,0,0},{0,0,0,0},{0,0,0,0} };
#pragma unroll
    for (int ks = 0; ks < 4; ++ks) {
      const float* ap = x + (size_t)(r0 + m16) * DDIM + ks * 32 + quad * 8;
      f32x4 a0 = *(const f32x4*)ap;
      f32x4 a1 = *(const f32x4*)(ap + 4);
      short8 a;
#pragma unroll
      for (int c = 0; c < 4; ++c) { a[c] = (short)f2bf(a0[c]); a[4 + c] = (short)f2bf(a1[c]); }
#pragma unroll
      for (int ct = 0; ct < 4; ++ct)
        acc[ct] = __builtin_amdgcn_mfma_f32_16x16x32_bf16(a, bfr[ks][ct], acc[ct], 0, 0, 0);
    }
#pragma unroll
    for (int ct = 0; ct < 4; ++ct) {
      int c = colhalf * 64 + ct * 16 + m16;
#pragma unroll
      for (int rg = 0; rg < 4; ++rg) {
        int r = r0 + quad * 4 + rg;
        outp[(size_t)r * DDIM + c] = f2bf(acc[ct][rg]);
      }
    }
  }
}

// ---------------- pass1: LDS-aggregated binning by dst>>8 -------------------
// 512 blocks x 256 threads x 8 edges. LDS histogram atomicAdd returns each
// edge's local rank; ONE global atomic per (block,bucket) reserves a
// contiguous range (8x fewer global atomics, still XCD-local via xs=pb&7,
// 512%8==0); edges then store at gb[cell]+rank.
__global__ __launch_bounds__(256) void pass1_bin(const int* __restrict__ ei,
                                                 u32* __restrict__ cursor,
                                                 u32* __restrict__ subb,
                                                 const u32* __restrict__ mode)
{
  __shared__ u32 lcnt[256];
  __shared__ u32 gb[256];
  int pb = blockIdx.x, t = threadIdx.x;
  lcnt[t] = 0;
  __syncthreads();

  int base = (pb * 256 + t) * 8;
  int s[8], d[8];
  if (mode[0]) {
    const long long* ei64 = (const long long*)ei;
#pragma unroll
    for (int k = 0; k < 4; ++k) {
      longlong2 sv = *(const longlong2*)(ei64 + base + 2 * k);
      longlong2 dv = *(const longlong2*)(ei64 + EE + base + 2 * k);
      s[2 * k] = (int)sv.x; s[2 * k + 1] = (int)sv.y;
      d[2 * k] = (int)dv.x; d[2 * k + 1] = (int)dv.y;
    }
  } else {
#pragma unroll
    for (int k = 0; k < 2; ++k) {
      int4 sv = *(const int4*)(ei + base + 4 * k);
      int4 dv = *(const int4*)(ei + EE + base + 4 * k);
      s[4 * k] = sv.x; s[4 * k + 1] = sv.y; s[4 * k + 2] = sv.z; s[4 * k + 3] = sv.w;
      d[4 * k] = dv.x; d[4 * k + 1] = dv.y; d[4 * k + 2] = dv.z; d[4 * k + 3] = dv.w;
    }
  }

  u32 rk[8];
#pragma unroll
  for (int e = 0; e < 8; ++e)
    rk[e] = atomicAdd(&lcnt[(u32)d[e] >> 8], 1u);
  __syncthreads();

  int xs = pb & 7;
  gb[t] = atomicAdd(&cursor[(t * 8 + xs) * 16], lcnt[t]);
  __syncthreads();

#pragma unroll
  for (int e = 0; e < 8; ++e) {
    u32 cell = (u32)d[e] >> 8;
    u32 pos  = gb[cell] + rk[e];
    if (pos < SUBCAP)
      subb[(size_t)(cell * 8 + xs) * SUBCAP + pos] =
          ((u32)(d[e] & 255) << 16) | (u32)s[e];
  }
}

// ---------------- pass2: CSR build, single-read rank-reuse ------------------
// 256 blocks (one per bucket) x 1024 threads. Each sub-bucket (<=768 entries)
// is read in ONE coalesced pass into registers; the count-phase LDS atomicAdd
// doubles as within-row rank; after the scan, entries are placed straight from
// registers. Edges read once, one LDS atomic per edge.
__global__ __launch_bounds__(1024) void pass2_build(const u32* __restrict__ cursor,
                                                    const u32* __restrict__ subb,
                                                    u32* __restrict__ rowptr,
                                                    u16* __restrict__ csr,
                                                    u32* __restrict__ perm)
{
  __shared__ u32 sh[256];
  __shared__ u32 cnt[256];
  __shared__ u32 cbase[256];
  __shared__ u32 hist[64];
  int b = blockIdx.x, t = threadIdx.x;

  if (t < 256) {
    u32 tot = 0;
#pragma unroll
    for (int x = 0; x < 8; ++x) tot += min(cursor[(t * 8 + x) * 16], (u32)SUBCAP);
    sh[t] = tot; cnt[t] = 0;
    if (t < 64) hist[t] = 0;
  }
  __syncthreads();
  for (int off = 1; off < 256; off <<= 1) {
    u32 v = 0, a = 0;
    if (t < 256) { v = sh[t]; a = (t >= off) ? sh[t - off] : 0u; }
    __syncthreads();
    if (t < 256) sh[t] = v + a;
    __syncthreads();
  }
  u32 base      = (b == 0) ? 0u : sh[b - 1];
  u32 total_all = sh[255];

  u32 sizes[8];
#pragma unroll
  for (int x = 0; x < 8; ++x) sizes[x] = min(cursor[(b * 8 + x) * 16], (u32)SUBCAP);

  // one coalesced read per sub-bucket; rank captured from count atomic
  u32 ent[8], rk[8];
  bool has[8];
#pragma unroll
  for (int x = 0; x < 8; ++x) {
    has[x] = ((u32)t < sizes[x]);
    ent[x] = 0; rk[x] = 0;
    if (has[x]) {
      u32 e = subb[(size_t)(b * 8 + x) * SUBCAP + t];
      ent[x] = e;
      rk[x]  = atomicAdd(&cnt[e >> 16], 1u);
    }
  }
  __syncthreads();

  u32 c = 0, dc = 0;
  if (t < 256) {
    c  = cnt[t];
    dc = min(c, 63u);
    atomicAdd(&hist[dc], 1u);                  // degree histogram
    sh[t] = c;
  }
  __syncthreads();
  for (int off = 1; off < 256; off <<= 1) {
    u32 v = 0, a = 0;
    if (t < 256) { v = sh[t]; a = (t >= off) ? sh[t - off] : 0u; }
    __syncthreads();
    if (t < 256) sh[t] = v + a;
    __syncthreads();
  }
  if (t < 256) {
    u32 loc = sh[t] - c;
    rowptr[b * 256 + t] = base + loc;
    cbase[t] = loc;
  }
  if (b == 255 && t == 255) rowptr[NN] = total_all;
  __syncthreads();
  if (t == 0) {
    u32 run = 0;
    for (int i = 0; i < 64; ++i) { u32 h = hist[i]; hist[i] = run; run += h; }
  }
  __syncthreads();
  if (t < 256) {
    u32 r = atomicAdd(&hist[dc], 1u);          // rank within bucket by degree
    perm[b * 256 + r] = b * 256 + t;
  }
  __syncthreads();

#pragma unroll
  for (int x = 0; x < 8; ++x) {
    if (has[x]) {
      u32 cell = ent[x] >> 16;
      csr[base + cbase[cell] + rk[x]] = (u16)(ent[x] & 0xFFFFu);
    }
  }
}

// ---------------- Fused attention + aggregation (no-max softmax) ------------
// Quarter-wave (16 lanes) per dst node, degree-sorted via perm (waves are
// degree-homogeneous). Ladder prefetch: issue ALL row-gathers of a 16/8/4
// chunk at once (named regs), sched_barrier(0) pins issue-before-consume,
// then consume in issue order -> counted vmcnt waits, up to 16 gathers in
// flight per 16-lane stream.
__device__ __forceinline__ void gat_item(u32x4 xw, const f32x2* av, const f32x2* rv,
                                         float& l, f32x2* acc)
{
  f32x2 xv[4];
  f32x2 sc2 = {0.f, 0.f};
#pragma unroll
  for (int i = 0; i < 4; ++i) {
    xv[i] = bfp2f(xw[i]);
    f32x2 t = xv[i] + rv[i];
    f32x2 lr = pk_max(t, t * NEG_SLOPE);        // leaky_relu
    sc2 += av[i] * lr;
  }
  float partial = sc2.x + sc2.y;
  partial += __shfl_xor(partial, 1);
  partial += __shfl_xor(partial, 2);
  partial += __shfl_xor(partial, 4);            // per-head score (8-lane group)
  float p = __expf(partial);
  l += p;
#pragma unroll
  for (int i = 0; i < 4; ++i) acc[i] += p * xv[i];
}

__global__ __launch_bounds__(256) void gat_fused(
    const u16* __restrict__ xl, const u16* __restrict__ xr,
    const u32* __restrict__ rowptr, const u16* __restrict__ csr,
    const u32* __restrict__ perm,
    const float* __restrict__ att, const float* __restrict__ bias,
    float* __restrict__ out)
{
  int tid  = threadIdx.x;
  int node = (int)perm[blockIdx.x * 16 + (tid >> 4)];
  int q    = tid & 15;
  int c0   = q * 8;
  const u16* __restrict__ xlc = xl + c0;

  // issue self-row gather early
  u32x4 SW = *(const u32x4*)(xlc + (size_t)node * DDIM);

  f32x2 av[4], rv[4];
  {
    f32x4 a0 = *(const f32x4*)(att + c0);
    f32x4 a1 = *(const f32x4*)(att + c0 + 4);
    av[0].x = a0[0]; av[0].y = a0[1]; av[1].x = a0[2]; av[1].y = a0[3];
    av[2].x = a1[0]; av[2].y = a1[1]; av[3].x = a1[2]; av[3].y = a1[3];
    u32x4 rw = *(const u32x4*)(xr + (size_t)node * DDIM + c0);
#pragma unroll
    for (int i = 0; i < 4; ++i) rv[i] = bfp2f(rw[i]);
  }

  float l = 0.f;
  f32x2 acc[4] = { {0,0},{0,0},{0,0},{0,0} };

  u32 rs  = rowptr[node];
  int deg = (int)(rowptr[node + 1] - rs);
  const u16* __restrict__ cp = csr + rs;

  gat_item(SW, av, rv, l, acc);                 // item 0 = self loop

  int j = 0;
  while (deg - j >= 16) {
    u32 i0  = cp[j+0],  i1  = cp[j+1],  i2  = cp[j+2],  i3  = cp[j+3];
    u32 i4  = cp[j+4],  i5  = cp[j+5],  i6  = cp[j+6],  i7  = cp[j+7];
    u32 i8  = cp[j+8],  i9  = cp[j+9],  i10 = cp[j+10], i11 = cp[j+11];
    u32 i12 = cp[j+12], i13 = cp[j+13], i14 = cp[j+14], i15 = cp[j+15];
    u32x4 L0  = *(const u32x4*)(xlc + (size_t)i0  * DDIM);
    u32x4 L1  = *(const u32x4*)(xlc + (size_t)i1  * DDIM);
    u32x4 L2  = *(const u32x4*)(xlc + (size_t)i2  * DDIM);
    u32x4 L3  = *(const u32x4*)(xlc + (size_t)i3  * DDIM);
    u32x4 L4  = *(const u32x4*)(xlc + (size_t)i4  * DDIM);
    u32x4 L5  = *(const u32x4*)(xlc + (size_t)i5  * DDIM);
    u32x4 L6  = *(const u32x4*)(xlc + (size_t)i6  * DDIM);
    u32x4 L7  = *(const u32x4*)(xlc + (size_t)i7  * DDIM);
    u32x4 L8  = *(const u32x4*)(xlc + (size_t)i8  * DDIM);
    u32x4 L9  = *(const u32x4*)(xlc + (size_t)i9  * DDIM);
    u32x4 L10 = *(const u32x4*)(xlc + (size_t)i10 * DDIM);
    u32x4 L11 = *(const u32x4*)(xlc + (size_t)i11 * DDIM);
    u32x4 L12 = *(const u32x4*)(xlc + (size_t)i12 * DDIM);
    u32x4 L13 = *(const u32x4*)(xlc + (size_t)i13 * DDIM);
    u32x4 L14 = *(const u32x4*)(xlc + (size_t)i14 * DDIM);
    u32x4 L15 = *(const u32x4*)(xlc + (size_t)i15 * DDIM);
    __builtin_amdgcn_sched_barrier(0);          // pin: all 16 issued before use
    gat_item(L0,  av, rv, l, acc);
    gat_item(L1,  av, rv, l, acc);
    gat_item(L2,  av, rv, l, acc);
    gat_item(L3,  av, rv, l, acc);
    gat_item(L4,  av, rv, l, acc);
    gat_item(L5,  av, rv, l, acc);
    gat_item(L6,  av, rv, l, acc);
    gat_item(L7,  av, rv, l, acc);
    gat_item(L8,  av, rv, l, acc);
    gat_item(L9,  av, rv, l, acc);
    gat_item(L10, av, rv, l, acc);
    gat_item(L11, av, rv, l, acc);
    gat_item(L12, av, rv, l, acc);
    gat_item(L13, av, rv, l, acc);
    gat_item(L14, av, rv, l, acc);
    gat_item(L15, av, rv, l, acc);
    j += 16;
  }
  if (deg - j >= 8) {
    u32 i0 = cp[j+0], i1 = cp[j+1], i2 = cp[j+2], i3 = cp[j+3];
    u32 i4 = cp[j+4], i5 = cp[j+5], i6 = cp[j+6], i7 = cp[j+7];
    u32x4 L0 = *(const u32x4*)(xlc + (size_t)i0 * DDIM);
    u32x4 L1 = *(const u32x4*)(xlc + (size_t)i1 * DDIM);
    u32x4 L2 = *(const u32x4*)(xlc + (size_t)i2 * DDIM);
    u32x4 L3 = *(const u32x4*)(xlc + (size_t)i3 * DDIM);
    u32x4 L4 = *(const u32x4*)(xlc + (size_t)i4 * DDIM);
    u32x4 L5 = *(const u32x4*)(xlc + (size_t)i5 * DDIM);
    u32x4 L6 = *(const u32x4*)(xlc + (size_t)i6 * DDIM);
    u32x4 L7 = *(const u32x4*)(xlc + (size_t)i7 * DDIM);
    __builtin_amdgcn_sched_barrier(0);
    gat_item(L0, av, rv, l, acc);
    gat_item(L1, av, rv, l, acc);
    gat_item(L2, av, rv, l, acc);
    gat_item(L3, av, rv, l, acc);
    gat_item(L4, av, rv, l, acc);
    gat_item(L5, av, rv, l, acc);
    gat_item(L6, av, rv, l, acc);
    gat_item(L7, av, rv, l, acc);
    j += 8;
  }
  if (deg - j >= 4) {
    u32 i0 = cp[j+0], i1 = cp[j+1], i2 = cp[j+2], i3 = cp[j+3];
    u32x4 L0 = *(const u32x4*)(xlc + (size_t)i0 * DDIM);
    u32x4 L1 = *(const u32x4*)(xlc + (size_t)i1 * DDIM);
    u32x4 L2 = *(const u32x4*)(xlc + (size_t)i2 * DDIM);
    u32x4 L3 = *(const u32x4*)(xlc + (size_t)i3 * DDIM);
    __builtin_amdgcn_sched_barrier(0);
    gat_item(L0, av, rv, l, acc);
    gat_item(L1, av, rv, l, acc);
    gat_item(L2, av, rv, l, acc);
    gat_item(L3, av, rv, l, acc);
    j += 4;
  }
  for (; j < deg; ++j) {
    u32 s = cp[j];
    u32x4 xw = *(const u32x4*)(xlc + (size_t)s * DDIM);
    gat_item(xw, av, rv, l, acc);
  }

  float inv = 1.f / l;
  f32x4 o0, o1;
  o0[0] = fmaf(acc[0].x, inv, bias[c0 + 0]);
  o0[1] = fmaf(acc[0].y, inv, bias[c0 + 1]);
  o0[2] = fmaf(acc[1].x, inv, bias[c0 + 2]);
  o0[3] = fmaf(acc[1].y, inv, bias[c0 + 3]);
  o1[0] = fmaf(acc[2].x, inv, bias[c0 + 4]);
  o1[1] = fmaf(acc[2].y, inv, bias[c0 + 5]);
  o1[2] = fmaf(acc[3].x, inv, bias[c0 + 6]);
  o1[3] = fmaf(acc[3].y, inv, bias[c0 + 7]);
  float* op = out + (size_t)node * DDIM + c0;
  *(f32x4*)op       = o0;
  *(f32x4*)(op + 4) = o1;
}

// ---------------- launch ----------------
extern "C" void kernel_launch(void* const* d_in, const int* in_sizes, int n_in,
                              void* d_out, int out_size, void* d_ws, size_t ws_size,
                              hipStream_t stream) {
  (void)in_sizes; (void)n_in; (void)out_size; (void)ws_size;
  const float* x    = (const float*)d_in[0];  // [N,128] fp32
  const int*   ei   = (const int*)d_in[1];    // [2,E] int64/int32 (detected)
  const float* Wl   = (const float*)d_in[2];  // [128,128] fp32
  const float* Wr   = (const float*)d_in[3];
  const float* attw = (const float*)d_in[4];  // [2,64] fp32
  const float* bias = (const float*)d_in[5];  // [128] fp32
  float* out = (float*)d_out;                 // [N,128] fp32

  char* w = (char*)d_ws;
  u16* xl     = (u16*)(w);                              // 16 MB
  u16* xr     = (u16*)(w + (16u << 20));                // 16 MB
  u32* subb   = (u32*)(w + (32u << 20));                // 6 MB
  u32* cursor = (u32*)(w + (38u << 20));                // 128 KB
  u32* mode   = (u32*)(w + (38u << 20) + (192u << 10)); // 8 B
  u32* rowptr = (u32*)(w + (38u << 20) + (256u << 10)); // 256 KB + 4
  u16* csr    = (u16*)(w + (39u << 20));                // 2 MB
  u16* wpack  = (u16*)(w + (41u << 20));                // 64 KB
  u32* perm   = (u32*)(w + (41u << 20) + (128u << 10)); // 256 KB

  init_misc<<<17, 256, 0, stream>>>(ei, mode, Wl, Wr, wpack, cursor);
  gemm_xlxr<<<NN / 64, 256, 0, stream>>>(x, wpack, xl, xr);
  pass1_bin<<<512, 256, 0, stream>>>(ei, cursor, subb, mode);
  pass2_build<<<256, 1024, 0, stream>>>(cursor, subb, rowptr, csr, perm);
  gat_fused<<<NN / 16, 256, 0, stream>>>(xl, xr, rowptr, csr, perm, attw, bias, out);
}

// Round 4
// 176.285 us; speedup vs baseline: 1.2706x; 1.1116x over previous
//
#include <hip/hip_runtime.h>

typedef unsigned short u16;
typedef unsigned int   u32;

#define NN     65536      // nodes = B*L = 8*8192
#define DDIM   128        // feature dim = H*C
#define EE     1048576    // edges (self loop handled inline, not in CSR)
#define NEG_SLOPE 0.2f
#define SUBCAP 640        // per (bucket, xcd-slot) capacity; mean 512, +5.6 sigma
#define BROW   8192       // fixed per-bucket CSR region (u16 entries, rows padded to 8)

typedef __attribute__((ext_vector_type(8))) short          short8;
typedef __attribute__((ext_vector_type(2))) float          f32x2;
typedef __attribute__((ext_vector_type(4))) float          f32x4;
typedef __attribute__((ext_vector_type(4))) u32            u32x4;

__device__ __forceinline__ float bf2f(u16 b) { return __uint_as_float(((u32)b) << 16); }
__device__ __forceinline__ u16 f2bf(float f) {
  u32 u = __float_as_uint(f);
  u += 0x7FFFu + ((u >> 16) & 1u);   // round-to-nearest-even
  return (u16)(u >> 16);
}
__device__ __forceinline__ f32x2 bfp2f(u32 w) {
  f32x2 r;
  r.x = __uint_as_float(w << 16);
  r.y = __uint_as_float(w & 0xFFFF0000u);
  return r;
}
__device__ __forceinline__ f32x2 pk_max(f32x2 a, f32x2 b) {
  f32x2 r; r.x = fmaxf(a.x, b.x); r.y = fmaxf(a.y, b.y); return r;
}

// ---- init: b0 = dtype detect; b1..b8 = W pack (parallel); b9..b16 = cursors -
__global__ void init_misc(const int* __restrict__ ei, u32* __restrict__ mode,
                          const float* __restrict__ Wl, const float* __restrict__ Wr,
                          u16* __restrict__ wpack, u32* __restrict__ cursor) {
  int t = threadIdx.x, b = blockIdx.x;
  if (b == 0) {
    if (t < 64) {
      int nz = (ei[2 * t + 1] != 0) ? 1 : 0;   // int64 storage => high words zero
      unsigned long long bal = __ballot(nz);
      if (t == 0) mode[0] = (bal == 0ull) ? 1u : 0u;   // 1 = int64
    }
    return;
  }
  if (b <= 8) {
    // one block per (colhalf, ks); 256 threads = 4 p-groups x 64 lanes; 2 p iters
    int pb = b - 1;
    int colhalf = pb >> 2, ks = pb & 3;
    int lane = t & 63, pp = t >> 6;
    int m16 = lane & 15, quad = lane >> 4;
#pragma unroll
    for (int pq = 0; pq < 2; ++pq) {
      int p = pq * 4 + pp;                     // 0..3 = Wl ct, 4..7 = Wr ct
      const float* W = (p < 4) ? Wl : Wr;
      int n = colhalf * 64 + (p & 3) * 16 + m16;
#pragma unroll
      for (int j = 0; j < 8; ++j) {
        int k = ks * 32 + quad * 8 + j;
        wpack[(((((colhalf * 4 + ks) * 8) + p) * 64 + lane) * 8) + j] = f2bf(W[k * DDIM + n]);
      }
    }
    return;
  }
  // b = 9..16: zero cursor lines (2048 sub-buckets x 16 u32)
  int i = (b - 9) * 256 + t;
#pragma unroll
  for (int k = 0; k < 16; ++k) cursor[i * 16 + k] = 0;
}

// ---------------- GEMM body: xl = x@Wl, xr = x@Wr (bf16 MFMA) ---------------
__device__ __forceinline__ void gemm_body(
    int pb, int tid,
    const float* __restrict__ x, const u16* __restrict__ wpack,
    u16* __restrict__ xl, u16* __restrict__ xr)
{
  int wave = tid >> 6;
  int lane = tid & 63;
  int m16  = lane & 15;
  int quad = lane >> 4;
  int mat     = wave >> 1;     // 0 = Wl -> xl, 1 = Wr -> xr
  int colhalf = wave & 1;
  int rowbase = pb * 64;

  const u16* wp = wpack + (size_t)colhalf * (4 * 8 * 64 * 8);
  short8 bfr[4][4];
#pragma unroll
  for (int ks = 0; ks < 4; ++ks)
#pragma unroll
    for (int ct = 0; ct < 4; ++ct)
      bfr[ks][ct] = *(const short8*)(wp + ((size_t)(ks * 8 + mat * 4 + ct) * 64 + lane) * 8);

  u16* outp = mat ? xr : xl;
#pragma unroll
  for (int rt = 0; rt < 4; ++rt) {
    int r0 = rowbase + rt * 16;
    f32x4 acc[4] = { {0,0,0,0},{0,0,0,0},{0,0,0,0},{0,0,0,0} };
#pragma unroll
    for (int ks = 0; ks < 4; ++ks) {
      const float* ap = x + (size_t)(r0 + m16) * DDIM + ks * 32 + quad * 8;
      f32x4 a0 = *(const f32x4*)ap;
      f32x4 a1 = *(const f32x4*)(ap + 4);
      short8 a;
#pragma unroll
      for (int c = 0; c < 4; ++c) { a[c] = (short)f2bf(a0[c]); a[4 + c] = (short)f2bf(a1[c]); }
#pragma unroll
      for (int ct = 0; ct < 4; ++ct)
        acc[ct] = __builtin_amdgcn_mfma_f32_16x16x32_bf16(a, bfr[ks][ct], acc[ct], 0, 0, 0);
    }
#pragma unroll
    for (int ct = 0; ct < 4; ++ct) {
      int c = colhalf * 64 + ct * 16 + m16;
#pragma unroll
      for (int rg = 0; rg < 4; ++rg) {
        int r = r0 + quad * 4 + rg;
        outp[(size_t)r * DDIM + c] = f2bf(acc[ct][rg]);
      }
    }
  }
}

// ---------------- pass1 body: LDS-aggregated binning by dst>>8 --------------
// 512 blocks x 256 threads x 8 edges. LDS histogram atomicAdd returns each
// edge's local rank; ONE global atomic per (block,bucket) reserves a
// contiguous range; still XCD-local (xs = pb&7; launched at base 1024, and
// 1024%8 == 0 so fused block 1024+pb runs on XCD pb&7).
__device__ __forceinline__ void pass1_body(
    int pb, int t,
    const int* __restrict__ ei, u32* __restrict__ cursor,
    u32* __restrict__ subb, const u32* __restrict__ mode,
    u32* lcnt, u32* gb)
{
  lcnt[t] = 0;
  __syncthreads();

  int base = (pb * 256 + t) * 8;
  int s[8], d[8];
  if (mode[0]) {
    const long long* ei64 = (const long long*)ei;
#pragma unroll
    for (int k = 0; k < 4; ++k) {
      longlong2 sv = *(const longlong2*)(ei64 + base + 2 * k);
      longlong2 dv = *(const longlong2*)(ei64 + EE + base + 2 * k);
      s[2 * k] = (int)sv.x; s[2 * k + 1] = (int)sv.y;
      d[2 * k] = (int)dv.x; d[2 * k + 1] = (int)dv.y;
    }
  } else {
#pragma unroll
    for (int k = 0; k < 2; ++k) {
      int4 sv = *(const int4*)(ei + base + 4 * k);
      int4 dv = *(const int4*)(ei + EE + base + 4 * k);
      s[4 * k] = sv.x; s[4 * k + 1] = sv.y; s[4 * k + 2] = sv.z; s[4 * k + 3] = sv.w;
      d[4 * k] = dv.x; d[4 * k + 1] = dv.y; d[4 * k + 2] = dv.z; d[4 * k + 3] = dv.w;
    }
  }

  u32 rk[8];
#pragma unroll
  for (int e = 0; e < 8; ++e)
    rk[e] = atomicAdd(&lcnt[(u32)d[e] >> 8], 1u);
  __syncthreads();

  int xs = pb & 7;
  gb[t] = atomicAdd(&cursor[(t * 8 + xs) * 16], lcnt[t]);
  __syncthreads();

#pragma unroll
  for (int e = 0; e < 8; ++e) {
    u32 cell = (u32)d[e] >> 8;
    u32 pos  = gb[cell] + rk[e];
    if (pos < SUBCAP)
      subb[(size_t)(cell * 8 + xs) * SUBCAP + pos] =
          ((u32)(d[e] & 255) << 16) | (u32)s[e];
  }
}

// ---------------- fused GEMM || pass1 (contiguous; both fast now) -----------
__global__ __launch_bounds__(256) void gemm_pass1(
    const float* __restrict__ x, const u16* __restrict__ wpack,
    u16* __restrict__ xl, u16* __restrict__ xr,
    const int* __restrict__ ei, u32* __restrict__ cursor,
    u32* __restrict__ subb, const u32* __restrict__ mode)
{
  __shared__ u32 lcnt[256];
  __shared__ u32 gb[256];
  int b = blockIdx.x;
  if (b < 1024) gemm_body(b, threadIdx.x, x, wpack, xl, xr);
  else          pass1_body(b - 1024, threadIdx.x, ei, cursor, subb, mode, lcnt, gb);
}

// ---------------- pass2: CSR build, fixed bucket regions, padded rows -------
// 256 blocks (one per bucket) x 1024 threads. Each sub-bucket (<=640 entries)
// read in ONE coalesced pass; count-phase LDS atomicAdd doubles as rank.
// CSR rows padded to 8 u16 (16B-aligned) inside a fixed BROW region per
// bucket; rowptr packs (start<<8 | deg) -> gat does ONE rowptr load and
// 16B-aligned vector index loads.
__global__ __launch_bounds__(1024) void pass2_build(const u32* __restrict__ cursor,
                                                    const u32* __restrict__ subb,
                                                    u32* __restrict__ rowptr,
                                                    u16* __restrict__ csr,
                                                    u32* __restrict__ perm)
{
  __shared__ u32 sh[256];
  __shared__ u32 cnt[256];
  __shared__ u32 cbase[256];
  __shared__ u32 hist[64];
  int b = blockIdx.x, t = threadIdx.x;

  if (t < 256) { cnt[t] = 0; if (t < 64) hist[t] = 0; }
  __syncthreads();

  u32 sizes[8];
#pragma unroll
  for (int x = 0; x < 8; ++x) sizes[x] = min(cursor[(b * 8 + x) * 16], (u32)SUBCAP);

  // one coalesced read per sub-bucket; rank captured from count atomic
  u32 ent[8], rk[8];
  bool has[8];
#pragma unroll
  for (int x = 0; x < 8; ++x) {
    has[x] = ((u32)t < sizes[x]);
    ent[x] = 0; rk[x] = 0;
    if (has[x]) {
      u32 e = subb[(size_t)(b * 8 + x) * SUBCAP + t];
      ent[x] = e;
      rk[x]  = atomicAdd(&cnt[e >> 16], 1u);
    }
  }
  __syncthreads();

  u32 c = 0, dc = 0, pc = 0;
  if (t < 256) {
    c  = cnt[t];
    dc = min(c, 63u);
    pc = (c + 7u) & ~7u;                       // pad row to 8 entries (16B)
    atomicAdd(&hist[dc], 1u);                  // degree histogram
    sh[t] = pc;
  }
  __syncthreads();
  for (int off = 1; off < 256; off <<= 1) {
    u32 v = 0, a = 0;
    if (t < 256) { v = sh[t]; a = (t >= off) ? sh[t - off] : 0u; }
    __syncthreads();
    if (t < 256) sh[t] = v + a;
    __syncthreads();
  }
  if (t < 256) {
    u32 loc = sh[t] - pc;                      // padded exclusive scan
    cbase[t] = loc;
    rowptr[b * 256 + t] = ((b * BROW + loc) << 8) | c;   // start<<8 | deg
  }
  __syncthreads();
  if (t == 0) {
    u32 run = 0;
    for (int i = 0; i < 64; ++i) { u32 h = hist[i]; hist[i] = run; run += h; }
  }
  __syncthreads();
  if (t < 256) {
    u32 r = atomicAdd(&hist[dc], 1u);          // rank within bucket by degree
    perm[b * 256 + r] = b * 256 + t;
  }
  __syncthreads();

#pragma unroll
  for (int x = 0; x < 8; ++x) {
    if (has[x]) {
      u32 cell = ent[x] >> 16;
      csr[b * BROW + cbase[cell] + rk[x]] = (u16)(ent[x] & 0xFFFFu);
    }
  }
}

// ---------------- Fused attention + aggregation (no-max softmax) ------------
// Quarter-wave (16 lanes) per dst node. LPT scheduling: block (tier,bucket)
// takes the (15-tier)-th degree-slice of its bucket -> highest-degree blocks
// dispatch FIRST, tail is short blocks. Indices vector-loaded (u32x4 over
// padded 16B-aligned CSR rows): 2 VMEM ops per 16 indices instead of 16.
__device__ __forceinline__ void gat_item(u32x4 xw, const f32x2* av, const f32x2* rv,
                                         float& l, f32x2* acc)
{
  f32x2 xv[4];
  f32x2 sc2 = {0.f, 0.f};
#pragma unroll
  for (int i = 0; i < 4; ++i) {
    xv[i] = bfp2f(xw[i]);
    f32x2 t = xv[i] + rv[i];
    f32x2 lr = pk_max(t, t * NEG_SLOPE);        // leaky_relu
    sc2 += av[i] * lr;
  }
  float partial = sc2.x + sc2.y;
  partial += __shfl_xor(partial, 1);
  partial += __shfl_xor(partial, 2);
  partial += __shfl_xor(partial, 4);            // per-head score (8-lane group)
  float p = __expf(partial);
  l += p;
#pragma unroll
  for (int i = 0; i < 4; ++i) acc[i] += p * xv[i];
}

__global__ __launch_bounds__(256) void gat_fused(
    const u16* __restrict__ xl, const u16* __restrict__ xr,
    const u32* __restrict__ rowptr, const u16* __restrict__ csr,
    const u32* __restrict__ perm,
    const float* __restrict__ att, const float* __restrict__ bias,
    float* __restrict__ out)
{
  int tid    = threadIdx.x;
  int bucket = blockIdx.x & 255;
  int tier   = blockIdx.x >> 8;                 // 0..15; tier 0 = top degrees
  int node   = (int)perm[bucket * 256 + (15 - tier) * 16 + (tid >> 4)];
  int q      = tid & 15;
  int c0     = q * 8;
  const u16* __restrict__ xlc = xl + c0;

  // issue self-row gather early
  u32x4 SW = *(const u32x4*)(xlc + (size_t)node * DDIM);

  f32x2 av[4], rv[4];
  {
    f32x4 a0 = *(const f32x4*)(att + c0);
    f32x4 a1 = *(const f32x4*)(att + c0 + 4);
    av[0].x = a0[0]; av[0].y = a0[1]; av[1].x = a0[2]; av[1].y = a0[3];
    av[2].x = a1[0]; av[2].y = a1[1]; av[3].x = a1[2]; av[3].y = a1[3];
    u32x4 rw = *(const u32x4*)(xr + (size_t)node * DDIM + c0);
#pragma unroll
    for (int i = 0; i < 4; ++i) rv[i] = bfp2f(rw[i]);
  }

  float l = 0.f;
  f32x2 acc[4] = { {0,0},{0,0},{0,0},{0,0} };

  u32 rp  = rowptr[node];
  u32 rs  = rp >> 8;                            // padded start (mult of 8)
  int deg = (int)(rp & 255u);
  const u16* __restrict__ cp = csr + rs;        // 16B-aligned

  gat_item(SW, av, rv, l, acc);                 // item 0 = self loop

  int j = 0;
  while (deg - j >= 16) {
    u32x4 iw0 = *(const u32x4*)(cp + j);
    u32x4 iw1 = *(const u32x4*)(cp + j + 8);
    u32 i0  = iw0.x & 0xFFFFu, i1  = iw0.x >> 16, i2  = iw0.y & 0xFFFFu, i3  = iw0.y >> 16;
    u32 i4  = iw0.z & 0xFFFFu, i5  = iw0.z >> 16, i6  = iw0.w & 0xFFFFu, i7  = iw0.w >> 16;
    u32 i8  = iw1.x & 0xFFFFu, i9  = iw1.x >> 16, i10 = iw1.y & 0xFFFFu, i11 = iw1.y >> 16;
    u32 i12 = iw1.z & 0xFFFFu, i13 = iw1.z >> 16, i14 = iw1.w & 0xFFFFu, i15 = iw1.w >> 16;
    u32x4 L0  = *(const u32x4*)(xlc + (size_t)i0  * DDIM);
    u32x4 L1  = *(const u32x4*)(xlc + (size_t)i1  * DDIM);
    u32x4 L2  = *(const u32x4*)(xlc + (size_t)i2  * DDIM);
    u32x4 L3  = *(const u32x4*)(xlc + (size_t)i3  * DDIM);
    u32x4 L4  = *(const u32x4*)(xlc + (size_t)i4  * DDIM);
    u32x4 L5  = *(const u32x4*)(xlc + (size_t)i5  * DDIM);
    u32x4 L6  = *(const u32x4*)(xlc + (size_t)i6  * DDIM);
    u32x4 L7  = *(const u32x4*)(xlc + (size_t)i7  * DDIM);
    u32x4 L8  = *(const u32x4*)(xlc + (size_t)i8  * DDIM);
    u32x4 L9  = *(const u32x4*)(xlc + (size_t)i9  * DDIM);
    u32x4 L10 = *(const u32x4*)(xlc + (size_t)i10 * DDIM);
    u32x4 L11 = *(const u32x4*)(xlc + (size_t)i11 * DDIM);
    u32x4 L12 = *(const u32x4*)(xlc + (size_t)i12 * DDIM);
    u32x4 L13 = *(const u32x4*)(xlc + (size_t)i13 * DDIM);
    u32x4 L14 = *(const u32x4*)(xlc + (size_t)i14 * DDIM);
    u32x4 L15 = *(const u32x4*)(xlc + (size_t)i15 * DDIM);
    __builtin_amdgcn_sched_barrier(0);          // pin: all 16 issued before use
    gat_item(L0,  av, rv, l, acc);
    gat_item(L1,  av, rv, l, acc);
    gat_item(L2,  av, rv, l, acc);
    gat_item(L3,  av, rv, l, acc);
    gat_item(L4,  av, rv, l, acc);
    gat_item(L5,  av, rv, l, acc);
    gat_item(L6,  av, rv, l, acc);
    gat_item(L7,  av, rv, l, acc);
    gat_item(L8,  av, rv, l, acc);
    gat_item(L9,  av, rv, l, acc);
    gat_item(L10, av, rv, l, acc);
    gat_item(L11, av, rv, l, acc);
    gat_item(L12, av, rv, l, acc);
    gat_item(L13, av, rv, l, acc);
    gat_item(L14, av, rv, l, acc);
    gat_item(L15, av, rv, l, acc);
    j += 16;
  }
  if (deg - j >= 8) {
    u32x4 iw = *(const u32x4*)(cp + j);
    u32 i0 = iw.x & 0xFFFFu, i1 = iw.x >> 16, i2 = iw.y & 0xFFFFu, i3 = iw.y >> 16;
    u32 i4 = iw.z & 0xFFFFu, i5 = iw.z >> 16, i6 = iw.w & 0xFFFFu, i7 = iw.w >> 16;
    u32x4 L0 = *(const u32x4*)(xlc + (size_t)i0 * DDIM);
    u32x4 L1 = *(const u32x4*)(xlc + (size_t)i1 * DDIM);
    u32x4 L2 = *(const u32x4*)(xlc + (size_t)i2 * DDIM);
    u32x4 L3 = *(const u32x4*)(xlc + (size_t)i3 * DDIM);
    u32x4 L4 = *(const u32x4*)(xlc + (size_t)i4 * DDIM);
    u32x4 L5 = *(const u32x4*)(xlc + (size_t)i5 * DDIM);
    u32x4 L6 = *(const u32x4*)(xlc + (size_t)i6 * DDIM);
    u32x4 L7 = *(const u32x4*)(xlc + (size_t)i7 * DDIM);
    __builtin_amdgcn_sched_barrier(0);
    gat_item(L0, av, rv, l, acc);
    gat_item(L1, av, rv, l, acc);
    gat_item(L2, av, rv, l, acc);
    gat_item(L3, av, rv, l, acc);
    gat_item(L4, av, rv, l, acc);
    gat_item(L5, av, rv, l, acc);
    gat_item(L6, av, rv, l, acc);
    gat_item(L7, av, rv, l, acc);
    j += 8;
  }
  if (deg - j >= 4) {
    uint2 iw = *(const uint2*)(cp + j);
    u32 i0 = iw.x & 0xFFFFu, i1 = iw.x >> 16, i2 = iw.y & 0xFFFFu, i3 = iw.y >> 16;
    u32x4 L0 = *(const u32x4*)(xlc + (size_t)i0 * DDIM);
    u32x4 L1 = *(const u32x4*)(xlc + (size_t)i1 * DDIM);
    u32x4 L2 = *(const u32x4*)(xlc + (size_t)i2 * DDIM);
    u32x4 L3 = *(const u32x4*)(xlc + (size_t)i3 * DDIM);
    __builtin_amdgcn_sched_barrier(0);
    gat_item(L0, av, rv, l, acc);
    gat_item(L1, av, rv, l, acc);
    gat_item(L2, av, rv, l, acc);
    gat_item(L3, av, rv, l, acc);
    j += 4;
  }
  for (; j < deg; ++j) {
    u32 s = cp[j];
    u32x4 xw = *(const u32x4*)(xlc + (size_t)s * DDIM);
    gat_item(xw, av, rv, l, acc);
  }

  float inv = 1.f / l;
  f32x4 o0, o1;
  o0[0] = fmaf(acc[0].x, inv, bias[c0 + 0]);
  o0[1] = fmaf(acc[0].y, inv, bias[c0 + 1]);
  o0[2] = fmaf(acc[1].x, inv, bias[c0 + 2]);
  o0[3] = fmaf(acc[1].y, inv, bias[c0 + 3]);
  o1[0] = fmaf(acc[2].x, inv, bias[c0 + 4]);
  o1[1] = fmaf(acc[2].y, inv, bias[c0 + 5]);
  o1[2] = fmaf(acc[3].x, inv, bias[c0 + 6]);
  o1[3] = fmaf(acc[3].y, inv, bias[c0 + 7]);
  float* op = out + (size_t)node * DDIM + c0;
  *(f32x4*)op       = o0;
  *(f32x4*)(op + 4) = o1;
}

// ---------------- launch ----------------
extern "C" void kernel_launch(void* const* d_in, const int* in_sizes, int n_in,
                              void* d_out, int out_size, void* d_ws, size_t ws_size,
                              hipStream_t stream) {
  (void)in_sizes; (void)n_in; (void)out_size; (void)ws_size;
  const float* x    = (const float*)d_in[0];  // [N,128] fp32
  const int*   ei   = (const int*)d_in[1];    // [2,E] int64/int32 (detected)
  const float* Wl   = (const float*)d_in[2];  // [128,128] fp32
  const float* Wr   = (const float*)d_in[3];
  const float* attw = (const float*)d_in[4];  // [2,64] fp32
  const float* bias = (const float*)d_in[5];  // [128] fp32
  float* out = (float*)d_out;                 // [N,128] fp32

  char* w = (char*)d_ws;
  u16* xl     = (u16*)(w);                              // 16 MB
  u16* xr     = (u16*)(w + (16u << 20));                // 16 MB
  u32* subb   = (u32*)(w + (32u << 20));                // 5 MB (2048 x 640 x 4B)
  u32* cursor = (u32*)(w + (37u << 20));                // 128 KB
  u32* mode   = (u32*)(w + (37u << 20) + (192u << 10)); // 8 B
  u32* rowptr = (u32*)(w + (37u << 20) + (256u << 10)); // 256 KB
  u16* csr    = (u16*)(w + (37u << 20) + (512u << 10)); // 4 MB (256 x 8192 u16)
  u16* wpack  = (u16*)(w + (41u << 20) + (512u << 10)); // 64 KB
  u32* perm   = (u32*)(w + (41u << 20) + (640u << 10)); // 256 KB

  init_misc<<<17, 256, 0, stream>>>(ei, mode, Wl, Wr, wpack, cursor);
  gemm_pass1<<<1536, 256, 0, stream>>>(x, wpack, xl, xr, ei, cursor, subb, mode);
  pass2_build<<<256, 1024, 0, stream>>>(cursor, subb, rowptr, csr, perm);
  gat_fused<<<NN / 16, 256, 0, stream>>>(xl, xr, rowptr, csr, perm, attw, bias, out);
}